// Round 2
// baseline (125.560 us; speedup 1.0000x reference)
//
#include <hip/hip_runtime.h>

// RGCN HighMem: out[dst[e]] += feat[src[e]] @ W[etypes[e]]
// E=200000, N=50000, R=64, D=32.
//
// Round 2: counting-sort edges by relation, then per-relation MFMA batching.
// W[r] lives in B-fragments in registers (loaded once per wave per relation)
// -> kills the 800 MB/launch L2 W-gather stream of the per-edge kernel.
// mfma_f32_16x16x32_bf16: M=16 edges, N=16 out-cols (x2 halves), K=32.
// Scatter-sum still via fp32 global atomics (6.4M / launch).

#define D 32
#define NRELS 64
#define BPR 16   // blocks per relation in main kernel

typedef __bf16 bf16x8 __attribute__((ext_vector_type(8)));
typedef float  f32x4  __attribute__((ext_vector_type(4)));

// ---- sort phase -----------------------------------------------------------

__global__ __launch_bounds__(256) void hist_kernel(
    const int* __restrict__ etypes, int n, int* __restrict__ hist)
{
    __shared__ int lh[NRELS];
    int tid = threadIdx.x;
    if (tid < NRELS) lh[tid] = 0;
    __syncthreads();
    for (int e = blockIdx.x * blockDim.x + tid; e < n; e += gridDim.x * blockDim.x)
        atomicAdd(&lh[etypes[e]], 1);
    __syncthreads();
    if (tid < NRELS) atomicAdd(&hist[tid], lh[tid]);
}

__global__ void scan_kernel(const int* __restrict__ hist,
                            int* __restrict__ base, int* __restrict__ cursor)
{
    int t = threadIdx.x;            // 64 threads = 1 wave
    int v = hist[t];
    int x = v;
    #pragma unroll
    for (int off = 1; off < 64; off <<= 1) {
        int y = __shfl_up(x, off, 64);
        if (t >= off) x += y;
    }
    base[t] = x - v;                // exclusive scan
    cursor[t] = x - v;
    if (t == 63) base[64] = x;      // total = E
}

__global__ __launch_bounds__(256) void scatter_kernel(
    const int* __restrict__ src, const int* __restrict__ dst,
    const int* __restrict__ etypes, int n, int* __restrict__ cursor,
    int* __restrict__ src_s, int* __restrict__ dst_s)
{
    __shared__ int lh[NRELS], lb[NRELS];
    int tid = threadIdx.x;
    if (tid < NRELS) lh[tid] = 0;
    __syncthreads();
    int e = blockIdx.x * blockDim.x + tid;
    int r = 0, rank = 0;
    if (e < n) { r = etypes[e]; rank = atomicAdd(&lh[r], 1); }
    __syncthreads();
    if (tid < NRELS) lb[tid] = (lh[tid] > 0) ? atomicAdd(&cursor[tid], lh[tid]) : 0;
    __syncthreads();
    if (e < n) {
        int p = lb[r] + rank;
        src_s[p] = src[e];
        dst_s[p] = dst[e];
    }
}

// ---- main: per-relation MFMA + atomic scatter -----------------------------

__global__ __launch_bounds__(256) void rgcn_mfma_kernel(
    const float* __restrict__ feat, const float* __restrict__ weight,
    const int* __restrict__ base, const int* __restrict__ src_s,
    const int* __restrict__ dst_s, float* __restrict__ out)
{
    int r    = blockIdx.x / BPR;
    int sub  = blockIdx.x % BPR;
    int wave = threadIdx.x >> 6;
    int lane = threadIdx.x & 63;
    int n    = lane & 15;        // A-row (edge-in-tile) for load; B/C col
    int quad = lane >> 4;

    int rbase = base[r];
    int count = base[r + 1] - rbase;
    if (count <= 0) return;
    int ntiles = (count + 15) >> 4;

    // B fragments: B[k][n], k = quad*8+j. Loaded once, reused for all tiles.
    const float* W = weight + (size_t)r * (D * D);
    bf16x8 b0, b1;
    #pragma unroll
    for (int j = 0; j < 8; ++j) {
        int k = quad * 8 + j;
        b0[j] = (__bf16)W[k * D + n];
        b1[j] = (__bf16)W[k * D + 16 + n];
    }

    for (int tile = sub * 4 + wave; tile < ntiles; tile += BPR * 4) {
        // A fragment: A[m][k], m = lane&15, k = quad*8+j  (8 consecutive floats)
        int pe = tile * 16 + n;
        int pc = pe < count ? pe : count - 1;   // clamp; masked at write
        int s  = src_s[rbase + pc];
        const float4* fp = (const float4*)(feat + (size_t)s * D + quad * 8);
        float4 fa = fp[0], fb = fp[1];
        bf16x8 a;
        a[0] = (__bf16)fa.x; a[1] = (__bf16)fa.y; a[2] = (__bf16)fa.z; a[3] = (__bf16)fa.w;
        a[4] = (__bf16)fb.x; a[5] = (__bf16)fb.y; a[6] = (__bf16)fb.z; a[7] = (__bf16)fb.w;

        f32x4 zero = {0.f, 0.f, 0.f, 0.f};
        f32x4 c0 = __builtin_amdgcn_mfma_f32_16x16x32_bf16(a, b0, zero, 0, 0, 0);
        f32x4 c1 = __builtin_amdgcn_mfma_f32_16x16x32_bf16(a, b1, zero, 0, 0, 0);

        // C layout: col = lane&15, row = quad*4 + v
        #pragma unroll
        for (int v = 0; v < 4; ++v) {
            int m  = quad * 4 + v;
            int p2 = tile * 16 + m;
            if (p2 < count) {
                int d = dst_s[rbase + p2];
                atomicAdd(out + (size_t)d * D + n,      c0[v]);
                atomicAdd(out + (size_t)d * D + 16 + n, c1[v]);
            }
        }
    }
}

// ---- fallback (round-1 kernel) if ws too small ----------------------------

__global__ __launch_bounds__(256) void rgcn_edge_kernel(
    const float* __restrict__ feat, const float* __restrict__ weight,
    const int* __restrict__ src, const int* __restrict__ dst,
    const int* __restrict__ etypes, float* __restrict__ out, int n_edges)
{
    int gid = blockIdx.x * blockDim.x + threadIdx.x;
    int e = gid >> 5;
    int o = gid & 31;
    if (e >= n_edges) return;
    int s = src[e], d = dst[e], r = etypes[e];
    const float* W = weight + (size_t)r * (D * D);
    float fv = feat[(size_t)s * D + o];
    float acc = 0.f;
    #pragma unroll
    for (int i = 0; i < D; ++i) {
        float fi = __shfl(fv, i, 32);
        acc = fmaf(fi, W[i * D + o], acc);
    }
    atomicAdd(&out[(size_t)d * D + o], acc);
}

// ---- launch ---------------------------------------------------------------

extern "C" void kernel_launch(void* const* d_in, const int* in_sizes, int n_in,
                              void* d_out, int out_size, void* d_ws, size_t ws_size,
                              hipStream_t stream) {
    const float* feat   = (const float*)d_in[0];
    const float* weight = (const float*)d_in[1];
    const int*   src    = (const int*)d_in[2];
    const int*   dst    = (const int*)d_in[3];
    const int*   etypes = (const int*)d_in[4];
    float*       out    = (float*)d_out;

    int E = in_sizes[2];

    hipMemsetAsync(d_out, 0, (size_t)out_size * sizeof(float), stream);

    size_t need = (size_t)(256 + 2 * (size_t)E) * sizeof(int);
    if (ws_size < need) {
        // not enough scratch: fall back to per-edge kernel
        long long total = (long long)E * 32;
        int grid = (int)((total + 255) / 256);
        rgcn_edge_kernel<<<grid, 256, 0, stream>>>(feat, weight, src, dst,
                                                   etypes, out, E);
        return;
    }

    int* wsi    = (int*)d_ws;
    int* hist   = wsi;            // 64
    int* basep  = wsi + 64;       // 65
    int* cursor = wsi + 160;      // 64
    int* src_s  = wsi + 256;      // E
    int* dst_s  = wsi + 256 + E;  // E

    hipMemsetAsync(d_ws, 0, NRELS * sizeof(int), stream);  // zero hist

    int blocks = (E + 255) / 256;
    hist_kernel<<<blocks, 256, 0, stream>>>(etypes, E, hist);
    scan_kernel<<<1, 64, 0, stream>>>(hist, basep, cursor);
    scatter_kernel<<<blocks, 256, 0, stream>>>(src, dst, etypes, E, cursor,
                                               src_s, dst_s);
    rgcn_mfma_kernel<<<NRELS * BPR, 256, 0, stream>>>(feat, weight, basep,
                                                      src_s, dst_s, out);
}

// Round 3
// 119.619 us; speedup vs baseline: 1.0497x; 1.0497x over previous
//
#include <hip/hip_runtime.h>

// RGCN HighMem: out[dst[e]] += feat[src[e]] @ W[etypes[e]]
// E=200000, N=50000, R=64, D=32.
//
// Round 3: single kernel. Entire W lives in LDS as bf16 (64*32*34*2B =
// 136 KB <= 160 KB/CU) -> removes the 800 MB/launch L2 W-gather stream of
// round 1 without the sort+multi-launch overhead of round 2 (which lost).
// One wave per edge: lane = (col-pair p, K-quarter q); 8 iters of
// shfl-broadcast feat * b32 LDS weight-pair; xor-reduce over q; 32 fp32
// atomics per edge (device-scope, XCD-safe).
//
// LDS bank math: b32 read at bank (17i + p) % 32; within one instruction
// i = q*8+j (j fixed) -> banks (8q + 17j + p) % 32 over q=0..3, p=0..15
// cover each bank exactly twice -> 2-way = free (m136).

#define D 32
#define NRELS 64
#define RSTRIDE 34          // ushort elems per (r,i) row in LDS (+2 pad)
#define BLOCK 1024
#define WPB 16              // waves per block
#define NBLOCKS 256         // 1 block/CU (LDS-limited anyway)

__global__ __launch_bounds__(BLOCK) void rgcn_ldsw_kernel(
    const float* __restrict__ feat,
    const float* __restrict__ weight,
    const int*   __restrict__ src,
    const int*   __restrict__ dst,
    const int*   __restrict__ etypes,
    float*       __restrict__ out,
    int n_edges, int chunk)
{
    __shared__ unsigned short lw[NRELS * D * RSTRIDE];   // 139264 B

    // Stage full W: fp32 global -> bf16 (RNE) LDS, padded rows.
    for (int idx = threadIdx.x; idx < NRELS * D * D; idx += BLOCK) {
        int r = idx >> 10, rem = idx & 1023;
        int i = rem >> 5,  o = rem & 31;
        unsigned int u = __float_as_uint(weight[idx]);
        unsigned short b = (unsigned short)((u + 0x7fffu + ((u >> 16) & 1u)) >> 16);
        lw[(r * D + i) * RSTRIDE + o] = b;
    }
    __syncthreads();

    int lane = threadIdx.x & 63;
    int wave = threadIdx.x >> 6;
    int p = lane & 15;      // col pair: cols 2p, 2p+1
    int q = lane >> 4;      // K quarter: i in [8q, 8q+8)
    int c = lane & 31;      // feat col this lane carries

    int gwave = blockIdx.x * WPB + wave;
    int begin = gwave * chunk;
    int end   = begin + chunk;
    if (end > n_edges) end = n_edges;

    auto process = [&](int e) {
        int eu = __builtin_amdgcn_readfirstlane(e);   // force s_load path
        int s = src[eu];
        int d = dst[eu];
        int r = etypes[eu];

        float fv = feat[(size_t)s * D + c];
        const unsigned short* wr = lw + r * (D * RSTRIDE);

        float a0 = 0.f, a1 = 0.f;
        #pragma unroll
        for (int j = 0; j < 8; ++j) {
            int i = q * 8 + j;
            float fi = __shfl(fv, i, 64);
            unsigned int wb = *(const unsigned int*)(wr + i * RSTRIDE + 2 * p);
            float w0 = __uint_as_float(wb << 16);            // col 2p
            float w1 = __uint_as_float(wb & 0xffff0000u);    // col 2p+1
            a0 = fmaf(fi, w0, a0);
            a1 = fmaf(fi, w1, a1);
        }
        // sum the 4 K-quarters (bits 4,5 of lane); p (bits 0-3) preserved
        a0 += __shfl_xor(a0, 16, 64);
        a0 += __shfl_xor(a0, 32, 64);
        a1 += __shfl_xor(a1, 16, 64);
        a1 += __shfl_xor(a1, 32, 64);
        if (q == 0)      atomicAdd(out + (size_t)d * D + 2 * p,     a0);
        else if (q == 1) atomicAdd(out + (size_t)d * D + 2 * p + 1, a1);
    };

    int e = begin;
    for (; e + 1 < end; e += 2) {   // 2 independent edges in flight (ILP)
        process(e);
        process(e + 1);
    }
    if (e < end) process(e);
}

extern "C" void kernel_launch(void* const* d_in, const int* in_sizes, int n_in,
                              void* d_out, int out_size, void* d_ws, size_t ws_size,
                              hipStream_t stream) {
    const float* feat   = (const float*)d_in[0];
    const float* weight = (const float*)d_in[1];
    const int*   src    = (const int*)d_in[2];
    const int*   dst    = (const int*)d_in[3];
    const int*   etypes = (const int*)d_in[4];
    float*       out    = (float*)d_out;

    int E = in_sizes[2];

    hipMemsetAsync(d_out, 0, (size_t)out_size * sizeof(float), stream);

    int total_waves = NBLOCKS * WPB;                 // 4096
    int chunk = (E + total_waves - 1) / total_waves; // 49 for E=200k

    rgcn_ldsw_kernel<<<NBLOCKS, BLOCK, 0, stream>>>(feat, weight, src, dst,
                                                    etypes, out, E, chunk);
}

// Round 4
// 97.038 us; speedup vs baseline: 1.2939x; 1.2327x over previous
//
#include <hip/hip_runtime.h>

// RGCN HighMem: out[dst[e]] += feat[src[e]] @ W[etypes[e]]
// E=200000, N=50000, R=64, D=32.
//
// Round 4: single fused kernel, NO workspace (using d_ws triggers a 268 MB
// per-iteration poison fill ~42 us — seen in round-2 profile only).
// Each block grabs a contiguous chunk of ~391 edges, buckets them by
// relation in LDS, then runs 16-edge MFMA tiles per relation using
// round-2's verified fragment mapping (A: m=lane&15,k=quad*8+j;
// B: k=quad*8+j,n=lane&15; C: col=lane&15,row=quad*4+v).
// This cuts DS-pipe ops from 16/edge (round 1/3 shuffles — the real
// serial cost) to ~0.4/edge and W L2 traffic from 800 MB to ~130 MB.
// Scatter stays 6.4M fp32 global atomics (contiguous 64B per dst row).

#define D 32
#define NRELS 64
#define BLOCK 512
#define WPB (BLOCK / 64)
#define GRID 512
#define MAXCHUNK BLOCK                       // one edge per thread in phase 1
#define MAXTILES (NRELS + MAXCHUNK / 16)     // sum ceil(c_r/16) bound

typedef __bf16 bf16x8 __attribute__((ext_vector_type(8)));
typedef float  f32x4  __attribute__((ext_vector_type(4)));

__global__ __launch_bounds__(BLOCK, 4) void rgcn_fused_kernel(
    const float* __restrict__ feat,
    const float* __restrict__ weight,
    const int*   __restrict__ src,
    const int*   __restrict__ dst,
    const int*   __restrict__ etypes,
    float*       __restrict__ out,
    int E, int chunk)
{
    __shared__ int cnt[NRELS];
    __shared__ int off[NRELS];
    __shared__ unsigned short list[MAXCHUNK];
    __shared__ unsigned short desc[MAXTILES];
    __shared__ int ntile_sh;

    int tid = threadIdx.x;
    int gbase = blockIdx.x * chunk;

    if (tid < NRELS) cnt[tid] = 0;
    __syncthreads();

    // ---- phase 1: bucket edges by relation (1 LDS atomic per edge) ----
    int my_r = -1, my_rank = 0;
    if (tid < chunk && gbase + tid < E) {
        my_r = etypes[gbase + tid];
        my_rank = atomicAdd(&cnt[my_r], 1);
    }
    __syncthreads();

    // ---- phase 2: wave 0 scans counts + builds tile descriptors ----
    if (tid < 64) {
        int c = cnt[tid];
        int x = c;
        #pragma unroll
        for (int o = 1; o < 64; o <<= 1) {
            int y = __shfl_up(x, o, 64);
            if (tid >= o) x += y;
        }
        off[tid] = x - c;                    // exclusive scan of counts

        int nt = (c + 15) >> 4;
        int tx = nt;
        #pragma unroll
        for (int o = 1; o < 64; o <<= 1) {
            int y = __shfl_up(tx, o, 64);
            if (tid >= o) tx += y;
        }
        int tbase = tx - nt;
        for (int t = 0; t < nt; ++t)
            desc[tbase + t] = (unsigned short)((tid << 8) | t);
        if (tid == 63) ntile_sh = tx;
    }
    __syncthreads();

    if (my_r >= 0) list[off[my_r] + my_rank] = (unsigned short)tid;
    int ntiles = ntile_sh;
    __syncthreads();

    // ---- phase 3: MFMA tiles + atomic scatter ----
    int wave = tid >> 6;
    int lane = tid & 63;
    int n    = lane & 15;
    int quad = lane >> 4;

    for (int ti = wave; ti < ntiles; ti += WPB) {
        int dsc = desc[ti];
        int r = dsc >> 8;
        int t = dsc & 255;
        int c = cnt[r];
        int mbase = t * 16;
        int mcnt = c - mbase; if (mcnt > 16) mcnt = 16;
        int lbase = off[r] + mbase;

        // B fragments from global W[r] (L1/L2-resident; 4 KB per tile)
        const float* W = weight + (size_t)r * (D * D);
        bf16x8 b0, b1;
        #pragma unroll
        for (int j = 0; j < 8; ++j) {
            int k = quad * 8 + j;
            b0[j] = (__bf16)W[k * D + n];
            b1[j] = (__bf16)W[k * D + 16 + n];
        }

        // A fragment: edge m = lane&15, k = quad*8+j (8 consecutive floats)
        int mm = (n < mcnt) ? n : 0;
        int le = list[lbase + mm];
        int s  = src[gbase + le];
        const float4* fp = (const float4*)(feat + (size_t)s * D + quad * 8);
        float4 fa = fp[0], fb = fp[1];
        bf16x8 a;
        a[0] = (__bf16)fa.x; a[1] = (__bf16)fa.y; a[2] = (__bf16)fa.z; a[3] = (__bf16)fa.w;
        a[4] = (__bf16)fb.x; a[5] = (__bf16)fb.y; a[6] = (__bf16)fb.z; a[7] = (__bf16)fb.w;

        f32x4 z = {0.f, 0.f, 0.f, 0.f};
        f32x4 c0 = __builtin_amdgcn_mfma_f32_16x16x32_bf16(a, b0, z, 0, 0, 0);
        f32x4 c1 = __builtin_amdgcn_mfma_f32_16x16x32_bf16(a, b1, z, 0, 0, 0);

        // C: col = lane&15 (out col n), row = quad*4+v (edge in tile)
        #pragma unroll
        for (int v = 0; v < 4; ++v) {
            int m2 = quad * 4 + v;
            if (m2 < mcnt) {
                int le2 = list[lbase + m2];
                int d = dst[gbase + le2];
                atomicAdd(out + (size_t)d * D + n,      c0[v]);
                atomicAdd(out + (size_t)d * D + 16 + n, c1[v]);
            }
        }
    }
}

// ---- fallback (round-1 kernel) for shapes the fused kernel can't chunk ----

__global__ __launch_bounds__(256) void rgcn_edge_kernel(
    const float* __restrict__ feat, const float* __restrict__ weight,
    const int* __restrict__ src, const int* __restrict__ dst,
    const int* __restrict__ etypes, float* __restrict__ out, int n_edges)
{
    int gid = blockIdx.x * blockDim.x + threadIdx.x;
    int e = gid >> 5;
    int o = gid & 31;
    if (e >= n_edges) return;
    int s = src[e], d = dst[e], r = etypes[e];
    const float* W = weight + (size_t)r * (D * D);
    float fv = feat[(size_t)s * D + o];
    float acc = 0.f;
    #pragma unroll
    for (int i = 0; i < D; ++i) {
        float fi = __shfl(fv, i, 32);
        acc = fmaf(fi, W[i * D + o], acc);
    }
    atomicAdd(&out[(size_t)d * D + o], acc);
}

extern "C" void kernel_launch(void* const* d_in, const int* in_sizes, int n_in,
                              void* d_out, int out_size, void* d_ws, size_t ws_size,
                              hipStream_t stream) {
    const float* feat   = (const float*)d_in[0];
    const float* weight = (const float*)d_in[1];
    const int*   src    = (const int*)d_in[2];
    const int*   dst    = (const int*)d_in[3];
    const int*   etypes = (const int*)d_in[4];
    float*       out    = (float*)d_out;

    int E = in_sizes[2];

    hipMemsetAsync(d_out, 0, (size_t)out_size * sizeof(float), stream);

    int chunk = (E + GRID - 1) / GRID;      // 391 for E=200k
    if (chunk <= MAXCHUNK) {
        rgcn_fused_kernel<<<GRID, BLOCK, 0, stream>>>(feat, weight, src, dst,
                                                      etypes, out, E, chunk);
    } else {
        long long total = (long long)E * 32;
        int grid = (int)((total + 255) / 256);
        rgcn_edge_kernel<<<grid, 256, 0, stream>>>(feat, weight, src, dst,
                                                   etypes, out, E);
    }
}

// Round 5
// 94.988 us; speedup vs baseline: 1.3219x; 1.0216x over previous
//
#include <hip/hip_runtime.h>

// RGCN HighMem: out[dst[e]] += feat[src[e]] @ W[etypes[e]]
// E=200000, N=50000, R=64, D=32.
//
// Round 5: round-4 fused structure + (a) prep kernel packing W into MFMA
// B-fragment order (128 KB in d_ws) and feat into bf16 rows (3.2 MB in
// d_ws) -> B-frag = 1 dwordx4/lane (was 16 scalar loads), A-frag = 1
// dwordx4 (was 2 float4); (b) chunk 782 / block 1024 -> ~76% tile fill
// (was 38%), ~21k tiles (was 33k); waves take contiguous relation-sorted
// tile runs. d_ws is FREE: the harness 0xAA-poisons it every iteration
// regardless of use (268 MB fill visible in all rounds' profiles).
// Scatter remains 6.4M fp32 global atomics — suspected floor; measured
// next if this round pins at >=30 us kernel time.

#define D 32
#define NRELS 64
#define BLOCK 1024
#define WPB (BLOCK / 64)
#define GRID 256
#define MAXCHUNK 1024
#define MAXTILES (NRELS + MAXCHUNK / 16)

typedef __bf16 bf16x8 __attribute__((ext_vector_type(8)));
typedef float  f32x4  __attribute__((ext_vector_type(4)));

static __device__ __forceinline__ unsigned int f2b(float x) {
    unsigned int u = __float_as_uint(x);
    return (u + 0x7fffu + ((u >> 16) & 1u)) >> 16;   // RNE bf16
}

// ---- prep: feat -> bf16 rows; W -> B-fragment-ordered bf16 ---------------

__global__ __launch_bounds__(256) void prep_kernel(
    const float* __restrict__ feat, const float* __restrict__ weight,
    unsigned short* __restrict__ featb,   // [N*32] bf16
    unsigned short* __restrict__ wpack,   // [64][2][64][8] bf16
    int n_nodes)
{
    int idx = blockIdx.x * 256 + threadIdx.x;
    int nfeat = n_nodes * 4;                    // one task = 8 elements
    if (idx < nfeat) {
        const float4* fp = (const float4*)(feat + (size_t)idx * 8);
        float4 a = fp[0], b = fp[1];
        uint4 o;
        o.x = f2b(a.x) | (f2b(a.y) << 16);
        o.y = f2b(a.z) | (f2b(a.w) << 16);
        o.z = f2b(b.x) | (f2b(b.y) << 16);
        o.w = f2b(b.z) | (f2b(b.w) << 16);
        ((uint4*)featb)[idx] = o;
    } else if (idx < nfeat + NRELS * 2 * 64) {
        int t = idx - nfeat;
        int r = t >> 7, half = (t >> 6) & 1, lane = t & 63;
        int quad = lane >> 4, n = lane & 15;
        const float* W = weight + (size_t)r * (D * D) + half * 16 + n;
        uint4 o;
        unsigned int v[8];
        #pragma unroll
        for (int j = 0; j < 8; ++j) v[j] = f2b(W[(quad * 8 + j) * D]);
        o.x = v[0] | (v[1] << 16);
        o.y = v[2] | (v[3] << 16);
        o.z = v[4] | (v[5] << 16);
        o.w = v[6] | (v[7] << 16);
        ((uint4*)wpack)[t] = o;
    }
}

// ---- main: bucket-by-relation + MFMA tiles + atomic scatter ---------------

__global__ __launch_bounds__(BLOCK, 4) void rgcn_fused_kernel(
    const unsigned short* __restrict__ featb,
    const unsigned short* __restrict__ wpack,
    const int* __restrict__ src,
    const int* __restrict__ dst,
    const int* __restrict__ etypes,
    float* __restrict__ out,
    int E, int chunk)
{
    __shared__ int cnt[NRELS];
    __shared__ int off[NRELS];
    __shared__ unsigned short list[MAXCHUNK];
    __shared__ unsigned short desc[MAXTILES];
    __shared__ int ntile_sh;

    int tid = threadIdx.x;
    int gbase = blockIdx.x * chunk;

    if (tid < NRELS) cnt[tid] = 0;
    __syncthreads();

    // phase 1: bucket edges by relation
    int my_r = -1, my_rank = 0;
    if (tid < chunk && gbase + tid < E) {
        my_r = etypes[gbase + tid];
        my_rank = atomicAdd(&cnt[my_r], 1);
    }
    __syncthreads();

    // phase 2: wave 0 scans counts + builds relation-sorted tile descriptors
    if (tid < 64) {
        int c = cnt[tid];
        int x = c;
        #pragma unroll
        for (int o = 1; o < 64; o <<= 1) {
            int y = __shfl_up(x, o, 64);
            if (tid >= o) x += y;
        }
        off[tid] = x - c;

        int nt = (c + 15) >> 4;
        int tx = nt;
        #pragma unroll
        for (int o = 1; o < 64; o <<= 1) {
            int y = __shfl_up(tx, o, 64);
            if (tid >= o) tx += y;
        }
        int tbase = tx - nt;
        for (int t = 0; t < nt; ++t)
            desc[tbase + t] = (unsigned short)((tid << 8) | t);
        if (tid == 63) ntile_sh = tx;
    }
    __syncthreads();

    if (my_r >= 0) list[off[my_r] + my_rank] = (unsigned short)tid;
    int ntiles = ntile_sh;
    __syncthreads();

    // phase 3: contiguous tile runs per wave (relation-sorted)
    int wave = tid >> 6;
    int lane = tid & 63;
    int n    = lane & 15;
    int quad = lane >> 4;

    int per = (ntiles + WPB - 1) / WPB;
    int t0 = wave * per;
    int t1 = t0 + per; if (t1 > ntiles) t1 = ntiles;

    for (int ti = t0; ti < t1; ++ti) {
        int dsc = desc[ti];
        int r = dsc >> 8;
        int t = dsc & 255;
        int c = cnt[r];
        int mbase = t * 16;
        int mcnt = c - mbase; if (mcnt > 16) mcnt = 16;
        int lbase = off[r] + mbase;

        // B fragments: one dwordx4 each from the packed buffer
        bf16x8 b0 = *(const bf16x8*)(wpack + ((size_t)(r * 2 + 0) * 64 + lane) * 8);
        bf16x8 b1 = *(const bf16x8*)(wpack + ((size_t)(r * 2 + 1) * 64 + lane) * 8);

        // A fragment: edge m = lane&15, k = quad*8+j — one dwordx4
        int mm = (n < mcnt) ? n : 0;
        int le = list[lbase + mm];
        int s  = src[gbase + le];
        bf16x8 a = *(const bf16x8*)(featb + (size_t)s * D + quad * 8);

        f32x4 z = {0.f, 0.f, 0.f, 0.f};
        f32x4 c0 = __builtin_amdgcn_mfma_f32_16x16x32_bf16(a, b0, z, 0, 0, 0);
        f32x4 c1 = __builtin_amdgcn_mfma_f32_16x16x32_bf16(a, b1, z, 0, 0, 0);

        // C: col = lane&15 (out col n), row = quad*4+v (edge in tile)
        #pragma unroll
        for (int v = 0; v < 4; ++v) {
            int m2 = quad * 4 + v;
            if (m2 < mcnt) {
                int le2 = list[lbase + m2];
                int d = dst[gbase + le2];
                atomicAdd(out + (size_t)d * D + n,      c0[v]);
                atomicAdd(out + (size_t)d * D + 16 + n, c1[v]);
            }
        }
    }
}

// ---- fallback (round-1 kernel) --------------------------------------------

__global__ __launch_bounds__(256) void rgcn_edge_kernel(
    const float* __restrict__ feat, const float* __restrict__ weight,
    const int* __restrict__ src, const int* __restrict__ dst,
    const int* __restrict__ etypes, float* __restrict__ out, int n_edges)
{
    int gid = blockIdx.x * blockDim.x + threadIdx.x;
    int e = gid >> 5;
    int o = gid & 31;
    if (e >= n_edges) return;
    int s = src[e], d = dst[e], r = etypes[e];
    const float* W = weight + (size_t)r * (D * D);
    float fv = feat[(size_t)s * D + o];
    float acc = 0.f;
    #pragma unroll
    for (int i = 0; i < D; ++i) {
        float fi = __shfl(fv, i, 32);
        acc = fmaf(fi, W[i * D + o], acc);
    }
    atomicAdd(&out[(size_t)d * D + o], acc);
}

// ---- launch ---------------------------------------------------------------

extern "C" void kernel_launch(void* const* d_in, const int* in_sizes, int n_in,
                              void* d_out, int out_size, void* d_ws, size_t ws_size,
                              hipStream_t stream) {
    const float* feat   = (const float*)d_in[0];
    const float* weight = (const float*)d_in[1];
    const int*   src    = (const int*)d_in[2];
    const int*   dst    = (const int*)d_in[3];
    const int*   etypes = (const int*)d_in[4];
    float*       out    = (float*)d_out;

    int N = in_sizes[0] / D;
    int R = in_sizes[1] / (D * D);
    int E = in_sizes[2];

    hipMemsetAsync(d_out, 0, (size_t)out_size * sizeof(float), stream);

    int chunk = (E + GRID - 1) / GRID;
    size_t featb_elems = (size_t)N * D;
    size_t need = (featb_elems + (size_t)NRELS * 2 * 64 * 8) * sizeof(unsigned short);

    if (R != NRELS || chunk > MAXCHUNK || ws_size < need) {
        long long total = (long long)E * 32;
        int grid = (int)((total + 255) / 256);
        rgcn_edge_kernel<<<grid, 256, 0, stream>>>(feat, weight, src, dst,
                                                   etypes, out, E);
        return;
    }

    unsigned short* featb = (unsigned short*)d_ws;
    unsigned short* wpack = featb + featb_elems;   // N*64 bytes offset, 16B-aligned

    int prep_tasks = N * 4 + NRELS * 2 * 64;
    int prep_grid = (prep_tasks + 255) / 256;
    prep_kernel<<<prep_grid, 256, 0, stream>>>(feat, weight, featb, wpack, N);

    rgcn_fused_kernel<<<GRID, BLOCK, 0, stream>>>(featb, wpack, src, dst,
                                                  etypes, out, E, chunk);
}